// Round 1
// baseline (745.512 us; speedup 1.0000x reference)
//
#include <hip/hip_runtime.h>
#include <cfloat>
#include <stdint.h>

// Problem dims (fixed): z_e [32,64,64,64] NCHW fp32, embedding [1024,64] fp32
// Flat rows n = b*4096 + h*64 + w  (N = 131072, D = 64, K = 1024)
// Out layout (concat, fp32): [0]=vq_loss, [1..8388608]=z_q NCHW,
//                            [8388609]=perplexity, [8388610..]=encodings [N,1024]
// ws: [0]=loss accum, [1..1024]=counts (int), [1025..2048]=e2
//
// R9 architecture (R8 + barrier-free vq_main main loop):
//  prep1: e2 exact pairwise + zero counts/loss
//  prep2: 3-way exact bf16 split of embedding -> MFMA B-fragment table,
//         stashed in the z_q region (overwritten later by vq_out)
//  k1:    per 64-row group: ip via 12x mfma_f32_16x16x32_bf16 per 16-code tile
//         (products hh,hm,mh,mm,hl,lh; ip err ~1e-9 ~ fp32 reorder noise).
//         CHANGE vs R8: B-frags are read global->VGPR directly (table is 384KB,
//         L2/L1-hot, all 4 waves read the same 6KB/tile) with a 2-deep named
//         register double buffer. No LDS staging, NO __syncthreads in the loop
//         -> no per-iteration vmcnt(0) drains. MFMA order preserved exactly.
//         dist = fmaf(-2, ip, x2+e2); argmin via packed (distbits<<32)|code u64
//         min (first-index ties); enc-zero stream fused; winners stashed in own
//         enc slice head (one barrier post-loop orders zeros before stash).
//  k2:    read winners -> z_q, enc 1.0s, loss partials, histogram
//  fin:   perplexity + vq_loss

typedef __attribute__((ext_vector_type(8))) short bf8v;
typedef __attribute__((ext_vector_type(4))) float f4v;

__device__ __forceinline__ unsigned short f2bf(float v) {  // RNE
  unsigned u = __float_as_uint(v);
  return (unsigned short)((u + 0x7FFFu + ((u >> 16) & 1u)) >> 16);
}
__device__ __forceinline__ float bf2f(unsigned short h) {
  return __uint_as_float(((unsigned)h) << 16);
}

__global__ __launch_bounds__(256) void vq_prep(const float* __restrict__ emb,
                                               float* __restrict__ ws) {
  #pragma clang fp contract(off)
  int gid = blockIdx.x * 256 + threadIdx.x;   // 0..1023
  if (gid == 0) ws[0] = 0.0f;
  ((int*)ws)[1 + gid] = 0;
  const float* e = emb + (gid << 6);
  float r[8];
  #pragma unroll
  for (int j = 0; j < 8; ++j) r[j] = e[j] * e[j];
  #pragma unroll
  for (int i = 8; i < 64; i += 8) {
    #pragma unroll
    for (int j = 0; j < 8; ++j) { float s = e[i + j] * e[i + j]; r[j] = r[j] + s; }
  }
  ws[1025 + gid] = ((r[0] + r[1]) + (r[2] + r[3])) + ((r[4] + r[5]) + (r[6] + r[7]));
}

// B-fragment table: entry e = ((nt*2+kk)*3+term)*64 + lane; 16B per entry.
// Lane ℓ of frag (nt,kk,term): codes c=16nt+(ℓ&15), k=32kk+8*(ℓ>>4)+j, j=0..7
// (mirrors the verified A layout A[m=lane&15][k=quad*8+j]; emb is row-major
// [code][d] = B^T, the m97 gemm_bt-validated pattern).
__global__ __launch_bounds__(256) void vq_prep_frags(const float* __restrict__ emb,
                                                     float* __restrict__ out) {
  int e = blockIdx.x * 256 + threadIdx.x;     // 0..24575
  int lane = e & 63, sub = e >> 6;
  int term = sub % 3, kk = (sub / 3) & 1, nt = sub / 6;
  int code = nt * 16 + (lane & 15);
  int d0 = kk * 32 + (lane >> 4) * 8;
  const float* src = emb + code * 64 + d0;
  unsigned short hs[8];
  #pragma unroll
  for (int j = 0; j < 8; ++j) {
    float v = src[j];
    unsigned short h = f2bf(v);  float r1 = v - bf2f(h);   // exact residual
    unsigned short m = f2bf(r1); float r2 = r1 - bf2f(m);  // exact residual
    unsigned short l = f2bf(r2);                           // exact (<=8 bits left)
    hs[j] = (term == 0) ? h : (term == 1) ? m : l;
  }
  uint4 p;
  p.x = (unsigned)hs[0] | ((unsigned)hs[1] << 16);
  p.y = (unsigned)hs[2] | ((unsigned)hs[3] << 16);
  p.z = (unsigned)hs[4] | ((unsigned)hs[5] << 16);
  p.w = (unsigned)hs[6] | ((unsigned)hs[7] << 16);
  ((uint4*)(out + 4))[e] = p;   // out+4 floats = +16B -> 16B aligned
}

// Load the 6 B-frags of tile ntv into named regs (static indexing, rule #20).
#define LOADB(P, ntv) do {                                        \
    const bf8v* _p = fp0 + (ntv) * 384;                           \
    P##0 = _p[0];   P##1 = _p[64];  P##2 = _p[128];               \
    P##3 = _p[192]; P##4 = _p[256]; P##5 = _p[320];               \
  } while (0)

// One 16-code tile: 12 MFMA (order identical to R8: per kk hh,hm,mh,mm,hl,lh),
// dist + packed-u64 argmin, fused enc-zero stream (row ntv of block region).
#define STEPB(P, ntv) do {                                                       \
    float e2v = e2s[(ntv) * 16 + (lane & 15)];                                   \
    f4v acc = {0.0f, 0.0f, 0.0f, 0.0f};                                          \
    acc = __builtin_amdgcn_mfma_f32_16x16x32_bf16(Ah[0], P##0, acc, 0, 0, 0);    \
    acc = __builtin_amdgcn_mfma_f32_16x16x32_bf16(Ah[0], P##1, acc, 0, 0, 0);    \
    acc = __builtin_amdgcn_mfma_f32_16x16x32_bf16(Am[0], P##0, acc, 0, 0, 0);    \
    acc = __builtin_amdgcn_mfma_f32_16x16x32_bf16(Am[0], P##1, acc, 0, 0, 0);    \
    acc = __builtin_amdgcn_mfma_f32_16x16x32_bf16(Ah[0], P##2, acc, 0, 0, 0);    \
    acc = __builtin_amdgcn_mfma_f32_16x16x32_bf16(Al[0], P##0, acc, 0, 0, 0);    \
    acc = __builtin_amdgcn_mfma_f32_16x16x32_bf16(Ah[1], P##3, acc, 0, 0, 0);    \
    acc = __builtin_amdgcn_mfma_f32_16x16x32_bf16(Ah[1], P##4, acc, 0, 0, 0);    \
    acc = __builtin_amdgcn_mfma_f32_16x16x32_bf16(Am[1], P##3, acc, 0, 0, 0);    \
    acc = __builtin_amdgcn_mfma_f32_16x16x32_bf16(Am[1], P##4, acc, 0, 0, 0);    \
    acc = __builtin_amdgcn_mfma_f32_16x16x32_bf16(Ah[1], P##5, acc, 0, 0, 0);    \
    acc = __builtin_amdgcn_mfma_f32_16x16x32_bf16(Al[1], P##3, acc, 0, 0, 0);    \
    unsigned code0 = (unsigned)((ntv) * 16 + (lane & 15));                       \
    _Pragma("unroll")                                                            \
    for (int r = 0; r < 4; ++r) {                                                \
      float tt = x2v[r] + e2v;                 /* fl(x2+e2) like numpy */        \
      float dd = fmaf(-2.0f, acc[r], tt);      /* == fl(t - fl(2ip)) */          \
      unsigned long long cand =                                                  \
          (((unsigned long long)__float_as_uint(dd)) << 32) | code0;             \
      if (cand < best[r]) best[r] = cand;      /* ties -> first index */         \
    }                                                                            \
    float2* ez = (float2*)(encbase + (ntv) * 1024) + t;                          \
    ez[0] = z2; ez[256] = z2;                                                    \
  } while (0)

__global__ __launch_bounds__(256, 4) void vq_main(const float* __restrict__ ze,
                                                  float* __restrict__ ws,
                                                  float* __restrict__ out) {
  __shared__ float xtile[64 * 68];                 // padded x tile (17.4 KB)
  __shared__ float e2s[1024];
  __shared__ float x2s[64];
  __shared__ float sx[256];

  int t = threadIdx.x;
  int w = __builtin_amdgcn_readfirstlane(t >> 6);  // wave id = m-tile 0..3
  int lane = t & 63;
  int g = blockIdx.x;
  int b = g >> 6, h = g & 63;
  int n0 = g << 6;

  // ---- stage x tile (row = spatial w = lane) + e2 ----
  const float* zebase = ze + ((size_t)b << 18) + (h << 6);
  #pragma unroll
  for (int i = 0; i < 16; ++i) {
    int d = w * 16 + i;
    xtile[lane * 68 + d] = zebase[d * 4096 + lane];
  }
  e2s[t] = ws[1025 + t];         e2s[256 + t] = ws[1281 + t];
  e2s[512 + t] = ws[1537 + t];   e2s[768 + t] = ws[1793 + t];
  __syncthreads();

  // ---- x2: numpy pairwise order, exactly; thread (row=lane, a=w) does r[2a],r[2a+1]
  {
    #pragma clang fp contract(off)
    const float* xr = xtile + lane * 68;
    int j0 = 2 * w, j1 = 2 * w + 1;
    float v0 = xr[j0], v1 = xr[j1];
    float ra = v0 * v0, rb = v1 * v1;
    #pragma unroll
    for (int p = 1; p < 8; ++p) {
      float s0 = xr[8 * p + j0]; s0 = s0 * s0; ra = ra + s0;
      float s1 = xr[8 * p + j1]; s1 = s1 * s1; rb = rb + s1;
    }
    sx[lane * 4 + w] = ra + rb;
  }
  __syncthreads();
  if (t < 64) x2s[t] = (sx[t * 4] + sx[t * 4 + 1]) + (sx[t * 4 + 2] + sx[t * 4 + 3]);
  __syncthreads();

  // ---- A-frags (VGPR-resident, built once): rows w*16..w*16+15 ----
  int qd = lane >> 4, rr = lane & 15;
  const float* xr = xtile + (w * 16 + rr) * 68;
  bf8v Ah[2], Am[2], Al[2];
  #pragma unroll
  for (int kk = 0; kk < 2; ++kk) {
    #pragma unroll
    for (int j = 0; j < 8; ++j) {
      float v = xr[kk * 32 + qd * 8 + j];
      unsigned short hh = f2bf(v);  float r1 = v - bf2f(hh);
      unsigned short mm = f2bf(r1); float r2 = r1 - bf2f(mm);
      unsigned short ll = f2bf(r2);
      Ah[kk][j] = (short)hh; Am[kk][j] = (short)mm; Al[kk][j] = (short)ll;
    }
  }
  float x2v[4];
  #pragma unroll
  for (int r = 0; r < 4; ++r) x2v[r] = x2s[w * 16 + qd * 4 + r];

  // B-frag table base (global, L2/L1-hot; 16B per lane-entry, 1KB per frag)
  const bf8v* fp0 = (const bf8v*)(out + 4) + lane;
  float* encbase = out + 8388610 + (size_t)n0 * 1024;
  const float2 z2 = make_float2(0.0f, 0.0f);

  unsigned long long best[4] = {~0ULL, ~0ULL, ~0ULL, ~0ULL};

  // ---- barrier-free main loop: 2-deep register double buffer ----
  bf8v Xa0, Xa1, Xa2, Xa3, Xa4, Xa5;
  bf8v Xb0, Xb1, Xb2, Xb3, Xb4, Xb5;
  LOADB(Xa, 0);
  #pragma unroll 1
  for (int nt = 0; nt < 64; nt += 2) {
    LOADB(Xb, nt + 1);              // prefetch odd tile (hides L1/L2 latency)
    STEPB(Xa, nt);
    if (nt < 62) LOADB(Xa, nt + 2); // prefetch next even tile
    STEPB(Xb, nt + 1);
  }

  // ---- per-quad cross-lane u64 argmin (rows w*16 + qd*4 + r) ----
  #pragma unroll
  for (int r = 0; r < 4; ++r) {
    unsigned long long bu = best[r];
    #pragma unroll
    for (int m = 1; m <= 8; m <<= 1) {
      unsigned long long o = __shfl_xor(bu, m, 64);
      if (o < bu) bu = o;
    }
    best[r] = bu;
  }
  // order all loop stores (incl. row-0 zeros) before the stash overwrite
  __syncthreads();
  if ((lane & 15) == 0) {
    #pragma unroll
    for (int r = 0; r < 4; ++r)
      ((int*)encbase)[w * 16 + qd * 4 + r] = (int)(best[r] & 0xFFFFFFFFu);
  }
}

__global__ __launch_bounds__(256) void vq_out(const float* __restrict__ ze,
                                              const float* __restrict__ emb,
                                              float* __restrict__ ws,
                                              float* __restrict__ out) {
  __shared__ float red[4];
  int g = blockIdx.x, t = threadIdx.x;
  int b = g >> 6, h = g & 63, n0 = g << 6;
  float* enc = out + 8388610;
  int* wp = (int*)(enc + (size_t)n0 * 1024);
  int row = t & 63;
  int gi = wp[row];
  __syncthreads();
  if (t < 64) ((float*)wp)[t] = 0.0f;       // clear winner-stash slots
  __syncthreads();
  if (t < 64) enc[(size_t)(n0 + t) * 1024 + gi] = 1.0f;

  const float* er = emb + gi * 64;
  const float* zr = ze + ((size_t)b << 18) + (h << 6) + row;
  float* qr = out + 1 + ((size_t)b << 18) + (h << 6) + row;
  float ls = 0.0f;
  #pragma unroll
  for (int i = 0; i < 16; ++i) {
    int d = (t >> 6) * 16 + i;
    float v = er[d];
    float df = v - zr[(size_t)d * 4096];
    ls = fmaf(df, df, ls);
    qr[(size_t)d * 4096] = v;
  }
  #pragma unroll
  for (int off = 32; off > 0; off >>= 1) ls += __shfl_down(ls, off, 64);
  if ((t & 63) == 0) red[t >> 6] = ls;
  __syncthreads();
  if (t == 0) atomicAdd(ws, (red[0] + red[1]) + (red[2] + red[3]));
  if (t < 64) atomicAdd((int*)ws + 1 + gi, 1);
}

__global__ __launch_bounds__(1024) void vq_fin(const float* __restrict__ ws,
                                               float* __restrict__ out) {
  __shared__ float sm[16];
  int t = threadIdx.x;  // 0..1023 = k
  const int* counts = (const int*)ws + 1;
  float c = (float)counts[t];
  float p = c * (1.0f / 131072.0f);
  float s = p * logf(p + 1e-10f);
  #pragma unroll
  for (int off = 32; off > 0; off >>= 1) s += __shfl_down(s, off, 64);
  if ((t & 63) == 0) sm[t >> 6] = s;
  __syncthreads();
  if (t == 0) {
    float v = 0.0f;
    #pragma unroll
    for (int i = 0; i < 16; ++i) v += sm[i];
    out[8388609] = expf(-v);               // perplexity
    float m = ws[0] / 8388608.0f;          // mean (z_q - z)^2
    out[0] = 0.25f * m + m;                // commitment + e2z
  }
}

extern "C" void kernel_launch(void* const* d_in, const int* in_sizes, int n_in,
                              void* d_out, int out_size, void* d_ws, size_t ws_size,
                              hipStream_t stream) {
  const float* ze  = (const float*)d_in[0];
  const float* emb = (const float*)d_in[1];
  float* out = (float*)d_out;
  float* ws  = (float*)d_ws;   // 2049 * 4B used
  vq_prep<<<4, 256, 0, stream>>>(emb, ws);
  vq_prep_frags<<<96, 256, 0, stream>>>(emb, out);
  vq_main<<<2048, 256, 0, stream>>>(ze, ws, out);
  vq_out<<<2048, 256, 0, stream>>>(ze, emb, ws, out);
  vq_fin<<<1, 1024, 0, stream>>>(ws, out);
}

// Round 2
// 641.489 us; speedup vs baseline: 1.1622x; 1.1622x over previous
//
#include <hip/hip_runtime.h>
#include <cfloat>
#include <stdint.h>

// Problem dims (fixed): z_e [32,64,64,64] NCHW fp32, embedding [1024,64] fp32
// Flat rows n = b*4096 + h*64 + w  (N = 131072, D = 64, K = 1024)
// Out layout (concat, fp32): [0]=vq_loss, [1..8388608]=z_q NCHW,
//                            [8388609]=perplexity, [8388610..]=encodings [N,1024]
// ws: [0]=loss accum, [1..1024]=counts (int), [1025..2048]=e2
//
// R10 architecture (R8 loop restored + vq_out fused into vq_main epilogue):
//  prep1: e2 exact pairwise + zero counts/loss
//  prep2: 3-way exact bf16 split of embedding -> MFMA B-fragment table,
//         stashed in the z_q region at out[4..98308] (b=0, d<24 slice).
//  k1:    per 64-row group: ip via 12x mfma_f32_16x16x32_bf16 per 16-code tile
//         (R8's LDS-staged double buffer, per-iteration barrier: measured-best),
//         dist = fmaf(-2, ip, x2+e2), packed-u64 argmin, enc-zero stream fused.
//         NEW: epilogue fuses the old vq_out for b!=0 blocks (1984 of 2048):
//         enc 1.0s, z_q writes, loss partials (z from LDS xtile -> no z_e
//         re-read), histogram. b==0 blocks would clobber the live frag table
//         with their z_q writes, so they keep the R8 winner-stash path.
//  k2:    cleanup = old vq_out, 64 blocks, handles b==0 rows only (runs after
//         vq_main, so the frag table is dead by then).
//  fin:   perplexity + vq_loss

typedef __attribute__((ext_vector_type(8))) short bf8v;
typedef __attribute__((ext_vector_type(4))) float f4v;

__device__ __forceinline__ unsigned short f2bf(float v) {  // RNE
  unsigned u = __float_as_uint(v);
  return (unsigned short)((u + 0x7FFFu + ((u >> 16) & 1u)) >> 16);
}
__device__ __forceinline__ float bf2f(unsigned short h) {
  return __uint_as_float(((unsigned)h) << 16);
}

__global__ __launch_bounds__(256) void vq_prep(const float* __restrict__ emb,
                                               float* __restrict__ ws) {
  #pragma clang fp contract(off)
  int gid = blockIdx.x * 256 + threadIdx.x;   // 0..1023
  if (gid == 0) ws[0] = 0.0f;
  ((int*)ws)[1 + gid] = 0;
  const float* e = emb + (gid << 6);
  float r[8];
  #pragma unroll
  for (int j = 0; j < 8; ++j) r[j] = e[j] * e[j];
  #pragma unroll
  for (int i = 8; i < 64; i += 8) {
    #pragma unroll
    for (int j = 0; j < 8; ++j) { float s = e[i + j] * e[i + j]; r[j] = r[j] + s; }
  }
  ws[1025 + gid] = ((r[0] + r[1]) + (r[2] + r[3])) + ((r[4] + r[5]) + (r[6] + r[7]));
}

// B-fragment table: entry e = ((nt*2+kk)*3+term)*64 + lane; 16B per entry.
// Lane ℓ of frag (nt,kk,term): codes c=16nt+(ℓ&15), k=32kk+8*(ℓ>>4)+j, j=0..7
// (mirrors the verified A layout A[m=lane&15][k=quad*8+j]; emb is row-major
// [code][d] = B^T, the m97 gemm_bt-validated pattern).
__global__ __launch_bounds__(256) void vq_prep_frags(const float* __restrict__ emb,
                                                     float* __restrict__ out) {
  int e = blockIdx.x * 256 + threadIdx.x;     // 0..24575
  int lane = e & 63, sub = e >> 6;
  int term = sub % 3, kk = (sub / 3) & 1, nt = sub / 6;
  int code = nt * 16 + (lane & 15);
  int d0 = kk * 32 + (lane >> 4) * 8;
  const float* src = emb + code * 64 + d0;
  unsigned short hs[8];
  #pragma unroll
  for (int j = 0; j < 8; ++j) {
    float v = src[j];
    unsigned short h = f2bf(v);  float r1 = v - bf2f(h);   // exact residual
    unsigned short m = f2bf(r1); float r2 = r1 - bf2f(m);  // exact residual
    unsigned short l = f2bf(r2);                           // exact (<=8 bits left)
    hs[j] = (term == 0) ? h : (term == 1) ? m : l;
  }
  uint4 p;
  p.x = (unsigned)hs[0] | ((unsigned)hs[1] << 16);
  p.y = (unsigned)hs[2] | ((unsigned)hs[3] << 16);
  p.z = (unsigned)hs[4] | ((unsigned)hs[5] << 16);
  p.w = (unsigned)hs[6] | ((unsigned)hs[7] << 16);
  ((uint4*)(out + 4))[e] = p;   // out+4 floats = +16B -> 16B aligned
}

__global__ __launch_bounds__(256, 4) void vq_main(const float* __restrict__ ze,
                                                  const float* __restrict__ emb,
                                                  float* __restrict__ ws,
                                                  float* __restrict__ out) {
  __shared__ float xtile[64 * 68];                 // padded x tile (17.4 KB)
  __shared__ __align__(16) short bbuf[2 * 6 * 64 * 8];  // B-frag dbuf (12 KB)
  __shared__ float e2s[1024];
  __shared__ float x2s[64];
  __shared__ float sx[256];
  __shared__ int warr[64];
  __shared__ float red[4];

  int t = threadIdx.x;
  int w = __builtin_amdgcn_readfirstlane(t >> 6);  // wave id = m-tile 0..3
  int lane = t & 63;
  int g = blockIdx.x;
  int b = g >> 6, h = g & 63;
  int n0 = g << 6;

  // ---- stage x tile (row = spatial w = lane) + e2 ----
  const float* zebase = ze + ((size_t)b << 18) + (h << 6);
  #pragma unroll
  for (int i = 0; i < 16; ++i) {
    int d = w * 16 + i;
    xtile[lane * 68 + d] = zebase[d * 4096 + lane];
  }
  e2s[t] = ws[1025 + t];         e2s[256 + t] = ws[1281 + t];
  e2s[512 + t] = ws[1537 + t];   e2s[768 + t] = ws[1793 + t];
  __syncthreads();

  // ---- x2: numpy pairwise order, exactly; thread (row=lane, a=w) does r[2a],r[2a+1]
  {
    #pragma clang fp contract(off)
    const float* xr = xtile + lane * 68;
    int j0 = 2 * w, j1 = 2 * w + 1;
    float v0 = xr[j0], v1 = xr[j1];
    float ra = v0 * v0, rb = v1 * v1;
    #pragma unroll
    for (int p = 1; p < 8; ++p) {
      float s0 = xr[8 * p + j0]; s0 = s0 * s0; ra = ra + s0;
      float s1 = xr[8 * p + j1]; s1 = s1 * s1; rb = rb + s1;
    }
    sx[lane * 4 + w] = ra + rb;
  }
  __syncthreads();
  if (t < 64) x2s[t] = (sx[t * 4] + sx[t * 4 + 1]) + (sx[t * 4 + 2] + sx[t * 4 + 3]);
  __syncthreads();

  // ---- A-frags (VGPR-resident, built once): rows w*16..w*16+15 ----
  int qd = lane >> 4, rr = lane & 15;
  const float* xr = xtile + (w * 16 + rr) * 68;
  bf8v Ah[2], Am[2], Al[2];
  #pragma unroll
  for (int kk = 0; kk < 2; ++kk) {
    #pragma unroll
    for (int j = 0; j < 8; ++j) {
      float v = xr[kk * 32 + qd * 8 + j];
      unsigned short hh = f2bf(v);  float r1 = v - bf2f(hh);
      unsigned short mm = f2bf(r1); float r2 = r1 - bf2f(mm);
      unsigned short ll = f2bf(r2);
      Ah[kk][j] = (short)hh; Am[kk][j] = (short)mm; Al[kk][j] = (short)ll;
    }
  }
  float x2v[4];
  #pragma unroll
  for (int r = 0; r < 4; ++r) x2v[r] = x2s[w * 16 + qd * 4 + r];

  const uint4* ft = (const uint4*)(out + 4);
  uint4* bput = (uint4*)bbuf;
  float* encbase = out + 8388610 + (size_t)n0 * 1024;
  const float2 z2 = make_float2(0.0f, 0.0f);

  // prologue: stage nt=0 frags (wave w stages f = w, w+4)
  for (int f = w; f < 6; f += 4) bput[f * 64 + lane] = ft[f * 64 + lane];
  __syncthreads();

  unsigned long long best[4] = {~0ULL, ~0ULL, ~0ULL, ~0ULL};

  #pragma unroll 1
  for (int nt = 0; nt < 64; ++nt) {
    int cur = nt & 1, nxt = cur ^ 1;
    uint4 pv0, pv1;
    if (nt < 63) {                       // issue next-tile loads early
      pv0 = ft[((nt + 1) * 6 + w) * 64 + lane];
      if (w < 2) pv1 = ft[((nt + 1) * 6 + w + 4) * 64 + lane];
    }
    float e2v = e2s[nt * 16 + (lane & 15)];
    f4v acc = {0.0f, 0.0f, 0.0f, 0.0f};
    const bf8v* bb = (const bf8v*)bbuf + cur * 6 * 64;
    #pragma unroll
    for (int kk = 0; kk < 2; ++kk) {
      bf8v Bh = bb[(kk * 3 + 0) * 64 + lane];
      bf8v Bm = bb[(kk * 3 + 1) * 64 + lane];
      bf8v Bl = bb[(kk * 3 + 2) * 64 + lane];
      acc = __builtin_amdgcn_mfma_f32_16x16x32_bf16(Ah[kk], Bh, acc, 0, 0, 0);
      acc = __builtin_amdgcn_mfma_f32_16x16x32_bf16(Ah[kk], Bm, acc, 0, 0, 0);
      acc = __builtin_amdgcn_mfma_f32_16x16x32_bf16(Am[kk], Bh, acc, 0, 0, 0);
      acc = __builtin_amdgcn_mfma_f32_16x16x32_bf16(Am[kk], Bm, acc, 0, 0, 0);
      acc = __builtin_amdgcn_mfma_f32_16x16x32_bf16(Ah[kk], Bl, acc, 0, 0, 0);
      acc = __builtin_amdgcn_mfma_f32_16x16x32_bf16(Al[kk], Bh, acc, 0, 0, 0);
    }
    unsigned code0 = (unsigned)(nt * 16 + (lane & 15));
    #pragma unroll
    for (int r = 0; r < 4; ++r) {
      float tt = x2v[r] + e2v;                 // fl(x2+e2) like numpy
      float dd = fmaf(-2.0f, acc[r], tt);      // == fl(t - fl(2ip)); 2ip exact
      unsigned long long cand =
          (((unsigned long long)__float_as_uint(dd)) << 32) | code0;
      if (cand < best[r]) best[r] = cand;      // ties -> lower code = first-index
    }
    // enc-zero stream: 1024 floats per nt (block covers its 256KB region)
    float2* ez = (float2*)(encbase + nt * 1024) + t;
    ez[0] = z2; ez[256] = z2;
    if (nt < 63) {
      bput[(nxt * 6 + w) * 64 + lane] = pv0;
      if (w < 2) bput[(nxt * 6 + w + 4) * 64 + lane] = pv1;
    }
    __syncthreads();
  }

  // ---- per-quad cross-lane u64 argmin (rows w*16 + qd*4 + r) ----
  #pragma unroll
  for (int r = 0; r < 4; ++r) {
    unsigned long long bu = best[r];
    #pragma unroll
    for (int m = 1; m <= 8; m <<= 1) {
      unsigned long long o = __shfl_xor(bu, m, 64);
      if (o < bu) bu = o;
    }
    best[r] = bu;
  }

  if (b == 0) {
    // frag table is live in this block's z_q slice -> R8 stash path; the
    // 64-block cleanup kernel (old vq_out) finishes these rows afterward.
    if ((lane & 15) == 0) {
      #pragma unroll
      for (int r = 0; r < 4; ++r)
        ((int*)encbase)[w * 16 + qd * 4 + r] = (int)(best[r] & 0xFFFFFFFFu);
    }
    return;
  }

  // ---- fused vq_out (b != 0): enc ones, z_q, loss, histogram ----
  if ((lane & 15) == 0) {
    #pragma unroll
    for (int r = 0; r < 4; ++r)
      warr[w * 16 + qd * 4 + r] = (int)(best[r] & 0xFFFFFFFFu);
  }
  __syncthreads();   // publish warr; also orders enc zeros before the 1.0s

  if (t < 64) {
    int gi = warr[t];
    encbase[(size_t)t * 1024 + gi] = 1.0f;
    atomicAdd((int*)ws + 1 + gi, 1);
  }

  {
    int row = t & 63;
    int gi = warr[row];
    const float* er = emb + (gi << 6);
    const float* xz = xtile + row * 68;
    float* qr = out + 1 + ((size_t)b << 18) + (h << 6) + row;
    float ls = 0.0f;
    #pragma unroll
    for (int i = 0; i < 16; ++i) {
      int d = (t >> 6) * 16 + i;
      float v = er[d];
      float df = v - xz[d];
      ls = fmaf(df, df, ls);
      qr[(size_t)d * 4096] = v;
    }
    #pragma unroll
    for (int off = 32; off > 0; off >>= 1) ls += __shfl_down(ls, off, 64);
    if ((t & 63) == 0) red[t >> 6] = ls;
    __syncthreads();
    if (t == 0) atomicAdd(ws, (red[0] + red[1]) + (red[2] + red[3]));
  }
}

// Cleanup for b==0 (64 blocks): identical to the old vq_out, g = h.
__global__ __launch_bounds__(256) void vq_out(const float* __restrict__ ze,
                                              const float* __restrict__ emb,
                                              float* __restrict__ ws,
                                              float* __restrict__ out) {
  __shared__ float red[4];
  int g = blockIdx.x, t = threadIdx.x;
  int b = g >> 6, h = g & 63, n0 = g << 6;
  float* enc = out + 8388610;
  int* wp = (int*)(enc + (size_t)n0 * 1024);
  int row = t & 63;
  int gi = wp[row];
  __syncthreads();
  if (t < 64) ((float*)wp)[t] = 0.0f;       // clear winner-stash slots
  __syncthreads();
  if (t < 64) enc[(size_t)(n0 + t) * 1024 + gi] = 1.0f;

  const float* er = emb + gi * 64;
  const float* zr = ze + ((size_t)b << 18) + (h << 6) + row;
  float* qr = out + 1 + ((size_t)b << 18) + (h << 6) + row;
  float ls = 0.0f;
  #pragma unroll
  for (int i = 0; i < 16; ++i) {
    int d = (t >> 6) * 16 + i;
    float v = er[d];
    float df = v - zr[(size_t)d * 4096];
    ls = fmaf(df, df, ls);
    qr[(size_t)d * 4096] = v;
  }
  #pragma unroll
  for (int off = 32; off > 0; off >>= 1) ls += __shfl_down(ls, off, 64);
  if ((t & 63) == 0) red[t >> 6] = ls;
  __syncthreads();
  if (t == 0) atomicAdd(ws, (red[0] + red[1]) + (red[2] + red[3]));
  if (t < 64) atomicAdd((int*)ws + 1 + gi, 1);
}

__global__ __launch_bounds__(1024) void vq_fin(const float* __restrict__ ws,
                                               float* __restrict__ out) {
  __shared__ float sm[16];
  int t = threadIdx.x;  // 0..1023 = k
  const int* counts = (const int*)ws + 1;
  float c = (float)counts[t];
  float p = c * (1.0f / 131072.0f);
  float s = p * logf(p + 1e-10f);
  #pragma unroll
  for (int off = 32; off > 0; off >>= 1) s += __shfl_down(s, off, 64);
  if ((t & 63) == 0) sm[t >> 6] = s;
  __syncthreads();
  if (t == 0) {
    float v = 0.0f;
    #pragma unroll
    for (int i = 0; i < 16; ++i) v += sm[i];
    out[8388609] = expf(-v);               // perplexity
    float m = ws[0] / 8388608.0f;          // mean (z_q - z)^2
    out[0] = 0.25f * m + m;                // commitment + e2z
  }
}

extern "C" void kernel_launch(void* const* d_in, const int* in_sizes, int n_in,
                              void* d_out, int out_size, void* d_ws, size_t ws_size,
                              hipStream_t stream) {
  const float* ze  = (const float*)d_in[0];
  const float* emb = (const float*)d_in[1];
  float* out = (float*)d_out;
  float* ws  = (float*)d_ws;   // 2049 * 4B used
  vq_prep<<<4, 256, 0, stream>>>(emb, ws);
  vq_prep_frags<<<96, 256, 0, stream>>>(emb, out);
  vq_main<<<2048, 256, 0, stream>>>(ze, emb, ws, out);
  vq_out<<<64, 256, 0, stream>>>(ze, emb, ws, out);   // b==0 cleanup
  vq_fin<<<1, 1024, 0, stream>>>(ws, out);
}